// Round 3
// baseline (8808.955 us; speedup 1.0000x reference)
//
#include <hip/hip_runtime.h>

typedef __attribute__((ext_vector_type(4))) float f32x4;
typedef __attribute__((ext_vector_type(8))) short bf16x8;
typedef __attribute__((ext_vector_type(4))) _Float16 f16x4;

constexpr int kB = 32;    // batch
constexpr int kS = 2048;  // seq len
constexpr int kH = 256;   // hidden
constexpr int kG = 768;   // 3*H

__device__ __forceinline__ short f2bf(float f) {
  unsigned u = __builtin_bit_cast(unsigned, f);
  u += 0x7fffu + ((u >> 16) & 1u);  // RNE
  return (short)(u >> 16);
}

__device__ __forceinline__ float fast_sigmoid(float x) {
  // 1/(1+2^(-x*log2e)) : mul, exp2, add, rcp (4 ops)
  return __builtin_amdgcn_rcpf(1.0f + __builtin_amdgcn_exp2f(x * -1.4426950408889634f));
}
__device__ __forceinline__ float fast_tanh(float x) {
  float e = __builtin_amdgcn_exp2f(x * 2.8853900817779268f);  // e^(2x)
  return 1.0f - 2.0f * __builtin_amdgcn_rcpf(1.0f + e);
}

__device__ __forceinline__ void load8(const float* p, float v[8]) {
  const float4 a = *(const float4*)p;
  const float4 b = *(const float4*)(p + 4);
  v[0] = a.x; v[1] = a.y; v[2] = a.z; v[3] = a.w;
  v[4] = b.x; v[5] = b.y; v[6] = b.z; v[7] = b.w;
}

// gx[t][g][b] = sum_k A[b][t][k] * W[g][k] + b_ih[g] + (g<512 ? b_hh[g] : 0)
// LAYER 0: A = fp32 [B][S][256].  LAYER 1: A = bf16 out0 [S][2][32][256] (K=512).
template <int LAYER>
__global__ __launch_bounds__(256) void gemm_gx(
    const void* __restrict__ Av, const float* __restrict__ W,
    const float* __restrict__ b_ih, const float* __restrict__ b_hh,
    _Float16* __restrict__ gx) {
  constexpr int K = (LAYER == 0) ? 256 : 512;
  __shared__ short As[64][40];  // stride 40 shorts = 80B: 16B-aligned rows, 2-way banks (free)
  __shared__ short Ws[64][40];
  const int tid = threadIdx.x;
  const int lane = tid & 63, wv = tid >> 6;
  const int quad = lane >> 4, l15 = lane & 15;
  const int m0 = blockIdx.y * 64, n0 = blockIdx.x * 64;
  const int srow = tid >> 2, kq = tid & 3;
  const int am = m0 + srow;
  const int b = am & 31, s = am >> 5;
  const float* Wrow = W + (size_t)(n0 + srow) * K;
  const float* Af = (const float*)Av + ((size_t)b * kS + s) * 256;
  const short* Ab = (const short*)Av + ((size_t)s * 64 + b) * 256;  // [s][dir][32][256]

  f32x4 acc[4] = {};

  for (int k0 = 0; k0 < K; k0 += 32) {
    const int k = k0 + kq * 8;
    short avs[8];
    if constexpr (LAYER == 0) {
      float v[8];
      load8(Af + k, v);
#pragma unroll
      for (int j = 0; j < 8; ++j) avs[j] = f2bf(v[j]);
    } else {
      *(uint4*)avs = *(const uint4*)(Ab + (size_t)(k >> 8) * 8192 + (k & 255));
    }
    float wv8[8];
    load8(Wrow + k, wv8);
    __syncthreads();  // previous iteration's LDS reads complete
#pragma unroll
    for (int j = 0; j < 8; ++j) As[srow][kq * 8 + j] = avs[j];
#pragma unroll
    for (int j = 0; j < 8; ++j) Ws[srow][kq * 8 + j] = f2bf(wv8[j]);
    __syncthreads();
    const bf16x8 bf = *(const bf16x8*)&Ws[wv * 16 + l15][quad * 8];
#pragma unroll
    for (int mt = 0; mt < 4; ++mt) {
      const bf16x8 af = *(const bf16x8*)&As[mt * 16 + l15][quad * 8];
      acc[mt] = __builtin_amdgcn_mfma_f32_16x16x32_bf16(af, bf, acc[mt], 0, 0, 0);
    }
  }
  const int col = n0 + wv * 16 + l15;
  const float bias = b_ih[col] + (col < 512 ? b_hh[col] : 0.0f);
#pragma unroll
  for (int mt = 0; mt < 4; ++mt) {
#pragma unroll
    for (int r = 0; r < 4; ++r) {
      const int m = m0 + mt * 16 + quad * 4 + r;
      gx[((size_t)(m >> 5) * kG + col) * 32 + (m & 31)] = (_Float16)(acc[mt][r] + bias);
    }
  }
}

union Frag8 {
  bf16x8 v;
  uint2 u2[2];
};

// One WG per (dir, batch-half): 16 batch rows, 512 threads (8 waves).
// v4 = v3 (two barriers, wlds kb=7, A-frag registerization, f2bf stores)
// + gx PREFETCH via 2x loop unroll: half-step A consumes gx registers loaded
//   during the previous half-step and issues the loads for half-step B.
//   Load->use distance becomes a full step (~2000 cyc), covering ~900 cyc HBM
//   latency. No rotation movs, no barrier change (v2's failure mode avoided).
// LAYER 0: out = bf16 [S][2][32][256] written via hlds b128 read + dwordx4 store.
// LAYER 1: out = fp32 [B][S][512] scalar stores (full precision).
template <int LAYER>
__global__ __launch_bounds__(512, 2) void gru_scan(
    const _Float16* __restrict__ gx,  // [S][768][32] (incl. b_ih + b_hh for r,z)
    const float* __restrict__ W_hh,   // [768][256]
    const float* __restrict__ b_hh,   // [768] (only n-part used here)
    void* __restrict__ outv,
    float* __restrict__ hn) {         // [2][32][256] slab for this layer
  __shared__ short hlds[16][264];  // stride 264: 16B-aligned rows, 2-way banks (free)
  __shared__ short wlds[768][36];  // kb=7 slice; stride 36 shorts = 72B (8B-aligned b64)

  const int tid = threadIdx.x;
  const int lane = tid & 63;
  const int w = tid >> 6;
  const int quad = lane >> 4, l15 = lane & 15;
  const int dir = blockIdx.x & 1;
  const int bbase = (blockIdx.x >> 1) * 16;

  for (int i = tid; i < 16 * 264; i += 512) (&hlds[0][0])[i] = 0;

  {  // stage W_hh[:, 224:256] -> LDS (bf16)
    const int kq = tid & 3, rb = tid >> 2;
#pragma unroll
    for (int j = 0; j < 6; ++j) {
      const int row = rb + j * 128;
      float v[8];
      load8(W_hh + (size_t)row * kH + 224 + kq * 8, v);
#pragma unroll
      for (int e = 0; e < 8; ++e) wlds[row][kq * 8 + e] = f2bf(v[e]);
    }
  }

  const int colH0 = w * 32 + l15;
  bf16x8 Bf[3][2][7];  // kb 0..6 register-resident
#pragma unroll
  for (int g3 = 0; g3 < 3; ++g3)
#pragma unroll
    for (int nt = 0; nt < 2; ++nt)
#pragma unroll
      for (int kb = 0; kb < 7; ++kb) {
        const int row = g3 * 256 + colH0 + nt * 16;
        float v[8];
        load8(W_hh + (size_t)row * kH + kb * 32 + quad * 8, v);
        bf16x8 f;
#pragma unroll
        for (int e = 0; e < 8; ++e) f[e] = f2bf(v[e]);
        Bf[g3][nt][kb] = f;
      }

  const float bhn[2] = {b_hh[512 + colH0], b_hh[512 + colH0 + 16]};
  float hprev[8] = {0, 0, 0, 0, 0, 0, 0, 0};

  short* out0 = (short*)outv;
  float* out1 = (float*)outv;

  // Per-thread time-invariant gx offsets.
  size_t gxoff[3][2];
#pragma unroll
  for (int g3 = 0; g3 < 3; ++g3)
#pragma unroll
    for (int nt = 0; nt < 2; ++nt)
      gxoff[g3][nt] = (size_t)(g3 * 256 + colH0 + nt * 16) * 32 + bbase + quad * 4;

  // Preload gx for the first step.
  f16x4 gxA[3][2], gxB[3][2];
  {
    const int t0 = dir ? (kS - 1) : 0;
    const _Float16* gxt = gx + (size_t)t0 * (kG * 32);
#pragma unroll
    for (int g3 = 0; g3 < 3; ++g3)
#pragma unroll
      for (int nt = 0; nt < 2; ++nt) gxA[g3][nt] = *(const f16x4*)(gxt + gxoff[g3][nt]);
  }

  __syncthreads();

#define CHAIN(G3, CC)                                                              \
  {                                                                                \
    _Pragma("unroll") for (int kb = 0; kb < 7; ++kb) {                             \
      _Pragma("unroll") for (int nt = 0; nt < 2; ++nt) {                           \
        CC[nt] = __builtin_amdgcn_mfma_f32_16x16x32_bf16(af[kb], Bf[G3][nt][kb],   \
                                                         CC[nt], 0, 0, 0);         \
      }                                                                            \
    }                                                                              \
    _Pragma("unroll") for (int nt = 0; nt < 2; ++nt) {                             \
      Frag8 bf;                                                                    \
      const int row = G3 * 256 + colH0 + nt * 16;                                  \
      bf.u2[0] = *(const uint2*)&wlds[row][quad * 8];                              \
      bf.u2[1] = *(const uint2*)&wlds[row][quad * 8 + 4];                          \
      CC[nt] = __builtin_amdgcn_mfma_f32_16x16x32_bf16(af[7], bf.v, CC[nt], 0, 0, 0); \
    }                                                                              \
  }

#define GSTEP(I, GXU, GXN)                                                         \
  {                                                                                \
    const int t = dir ? (kS - 1 - (I)) : (I);                                      \
    /* A-frags (h(t-1)) loaded ONCE, shared by all three gate chains. */           \
    bf16x8 af[8];                                                                  \
    _Pragma("unroll") for (int kb = 0; kb < 8; ++kb) {                             \
      af[kb] = *(const bf16x8*)&hlds[l15][kb * 32 + quad * 8];                     \
    }                                                                              \
    /* Prefetch NEXT step's gx (consumed one half-step later). */                  \
    {                                                                              \
      const int In = ((I) + 1 < kS) ? (I) + 1 : (I);                               \
      const int tn = dir ? (kS - 1 - In) : In;                                     \
      const _Float16* gxtn = gx + (size_t)tn * (kG * 32);                          \
      _Pragma("unroll") for (int g3 = 0; g3 < 3; ++g3) {                           \
        _Pragma("unroll") for (int nt = 0; nt < 2; ++nt) {                         \
          GXN[g3][nt] = *(const f16x4*)(gxtn + gxoff[g3][nt]);                     \
        }                                                                          \
      }                                                                            \
    }                                                                              \
    f32x4 C0[2] = {}, C1[2] = {}, C2[2] = {};                                      \
    CHAIN(0, C0) /* r-gate accumulators first */                                   \
    CHAIN(2, C2) /* n-gate */                                                      \
    float rr[2][4]; /* r sigmoids overlap the z-chain below */                     \
    _Pragma("unroll") for (int nt = 0; nt < 2; ++nt) {                             \
      _Pragma("unroll") for (int r = 0; r < 4; ++r) {                              \
        rr[nt][r] = fast_sigmoid((float)GXU[0][nt][r] + C0[nt][r]);                \
      }                                                                            \
    }                                                                              \
    CHAIN(1, C1) /* z-gate last */                                                 \
    float nn[2][4];                                                                \
    _Pragma("unroll") for (int nt = 0; nt < 2; ++nt) {                             \
      _Pragma("unroll") for (int r = 0; r < 4; ++r) {                              \
        nn[nt][r] = fast_tanh((float)GXU[2][nt][r] + rr[nt][r] * (C2[nt][r] + bhn[nt])); \
      }                                                                            \
    }                                                                              \
    __syncthreads(); /* barrier-1: all hlds A-frag reads complete */               \
    _Pragma("unroll") for (int nt = 0; nt < 2; ++nt) {                             \
      _Pragma("unroll") for (int r = 0; r < 4; ++r) {                              \
        const float zz = fast_sigmoid((float)GXU[1][nt][r] + C1[nt][r]);           \
        const int e = nt * 4 + r;                                                  \
        const float h = nn[nt][r] + zz * (hprev[e] - nn[nt][r]);                   \
        hprev[e] = h;                                                              \
        hlds[quad * 4 + r][colH0 + nt * 16] = f2bf(h);                             \
        if constexpr (LAYER == 1) {                                                \
          out1[((size_t)(bbase + quad * 4 + r) * kS + t) * 512 + dir * 256 +       \
               colH0 + nt * 16] = h;                                               \
        }                                                                          \
      }                                                                            \
    }                                                                              \
    __syncthreads(); /* barrier-2: h(t) visible */                                 \
    if constexpr (LAYER == 0) { /* vectorized bf16 out0 store via hlds */          \
      const int srow = tid >> 5, schunk = tid & 31;                                \
      *(uint4*)(out0 + (((size_t)t * 2 + dir) * 32 + bbase + srow) * 256 +         \
                schunk * 8) = *(const uint4*)&hlds[srow][schunk * 8];              \
    }                                                                              \
  }

  for (int i = 0; i < kS; i += 2) {
    GSTEP(i, gxA, gxB)
    GSTEP(i + 1, gxB, gxA)
  }
#undef GSTEP
#undef CHAIN

#pragma unroll
  for (int nt = 0; nt < 2; ++nt)
#pragma unroll
    for (int r = 0; r < 4; ++r)
      hn[(size_t)(dir * kB + bbase + quad * 4 + r) * kH + colH0 + nt * 16] =
          hprev[nt * 4 + r];
}

extern "C" void kernel_launch(void* const* d_in, const int* in_sizes, int n_in,
                              void* d_out, int out_size, void* d_ws, size_t ws_size,
                              hipStream_t stream) {
  const float* x     = (const float*)d_in[0];  // [B][S][256]
  const float* W_ih0 = (const float*)d_in[1];  // [768][256]
  const float* W_hh0 = (const float*)d_in[2];  // [768][256]
  const float* b_ih0 = (const float*)d_in[3];
  const float* b_hh0 = (const float*)d_in[4];
  const float* W_ih1 = (const float*)d_in[5];  // [768][512]
  const float* W_hh1 = (const float*)d_in[6];  // [768][256]
  const float* b_ih1 = (const float*)d_in[7];
  const float* b_hh1 = (const float*)d_in[8];

  float* out1 = (float*)d_out;                  // [B][S][512]
  float* hn = out1 + (size_t)kB * kS * 512;     // [4][B][H]

  _Float16* gxb = (_Float16*)d_ws;  // [S][768][32] fp16 (96 MB)
  short* out0 = (short*)((char*)d_ws + (size_t)kS * kB * kG * 2);  // bf16 [S][2][32][256] (64 MB)

  dim3 ggrid(kG / 64, (kS * kB) / 64);

  // Layer 0
  gemm_gx<0><<<ggrid, 256, 0, stream>>>(x, W_ih0, b_ih0, b_hh0, gxb);
  gru_scan<0><<<dim3(4), 512, 0, stream>>>(gxb, W_hh0, b_hh0, out0, hn);
  // Layer 1
  gemm_gx<1><<<ggrid, 256, 0, stream>>>(out0, W_ih1, b_ih1, b_hh1, gxb);
  gru_scan<1><<<dim3(4), 512, 0, stream>>>(gxb, W_hh1, b_hh1, out1, hn + 2 * kB * kH);
}

// Round 6
// 7592.265 us; speedup vs baseline: 1.1603x; 1.1603x over previous
//
#include <hip/hip_runtime.h>

typedef __attribute__((ext_vector_type(4))) float f32x4;
typedef __attribute__((ext_vector_type(8))) short bf16x8;
typedef __attribute__((ext_vector_type(4))) _Float16 f16x4;

constexpr int kB = 32;    // batch
constexpr int kS = 2048;  // seq len
constexpr int kH = 256;   // hidden
constexpr int kG = 768;   // 3*H

__device__ __forceinline__ short f2bf(float f) {
  unsigned u = __builtin_bit_cast(unsigned, f);
  u += 0x7fffu + ((u >> 16) & 1u);  // RNE
  return (short)(u >> 16);
}

__device__ __forceinline__ float fast_sigmoid(float x) {
  // 1/(1+2^(-x*log2e)) : mul, exp2, add, rcp (4 ops)
  return __builtin_amdgcn_rcpf(1.0f + __builtin_amdgcn_exp2f(x * -1.4426950408889634f));
}
__device__ __forceinline__ float fast_tanh(float x) {
  float e = __builtin_amdgcn_exp2f(x * 2.8853900817779268f);  // e^(2x)
  return 1.0f - 2.0f * __builtin_amdgcn_rcpf(1.0f + e);
}

__device__ __forceinline__ void load8(const float* p, float v[8]) {
  const float4 a = *(const float4*)p;
  const float4 b = *(const float4*)(p + 4);
  v[0] = a.x; v[1] = a.y; v[2] = a.z; v[3] = a.w;
  v[4] = b.x; v[5] = b.y; v[6] = b.z; v[7] = b.w;
}

// gx[t][g][b] = sum_k A[b][t][k] * W[g][k] + b_ih[g] + (g<512 ? b_hh[g] : 0)
// LAYER 0: A = fp32 [B][S][256].  LAYER 1: A = bf16 out0 [S][2][32][256] (K=512).
template <int LAYER>
__global__ __launch_bounds__(256) void gemm_gx(
    const void* __restrict__ Av, const float* __restrict__ W,
    const float* __restrict__ b_ih, const float* __restrict__ b_hh,
    _Float16* __restrict__ gx) {
  constexpr int K = (LAYER == 0) ? 256 : 512;
  __shared__ short As[64][40];  // stride 40 shorts = 80B: 16B-aligned rows, 2-way banks (free)
  __shared__ short Ws[64][40];
  const int tid = threadIdx.x;
  const int lane = tid & 63, wv = tid >> 6;
  const int quad = lane >> 4, l15 = lane & 15;
  const int m0 = blockIdx.y * 64, n0 = blockIdx.x * 64;
  const int srow = tid >> 2, kq = tid & 3;
  const int am = m0 + srow;
  const int b = am & 31, s = am >> 5;
  const float* Wrow = W + (size_t)(n0 + srow) * K;
  const float* Af = (const float*)Av + ((size_t)b * kS + s) * 256;
  const short* Ab = (const short*)Av + ((size_t)s * 64 + b) * 256;  // [s][dir][32][256]

  f32x4 acc[4] = {};

  for (int k0 = 0; k0 < K; k0 += 32) {
    const int k = k0 + kq * 8;
    short avs[8];
    if constexpr (LAYER == 0) {
      float v[8];
      load8(Af + k, v);
#pragma unroll
      for (int j = 0; j < 8; ++j) avs[j] = f2bf(v[j]);
    } else {
      *(uint4*)avs = *(const uint4*)(Ab + (size_t)(k >> 8) * 8192 + (k & 255));
    }
    float wv8[8];
    load8(Wrow + k, wv8);
    __syncthreads();  // previous iteration's LDS reads complete
#pragma unroll
    for (int j = 0; j < 8; ++j) As[srow][kq * 8 + j] = avs[j];
#pragma unroll
    for (int j = 0; j < 8; ++j) Ws[srow][kq * 8 + j] = f2bf(wv8[j]);
    __syncthreads();
    const bf16x8 bf = *(const bf16x8*)&Ws[wv * 16 + l15][quad * 8];
#pragma unroll
    for (int mt = 0; mt < 4; ++mt) {
      const bf16x8 af = *(const bf16x8*)&As[mt * 16 + l15][quad * 8];
      acc[mt] = __builtin_amdgcn_mfma_f32_16x16x32_bf16(af, bf, acc[mt], 0, 0, 0);
    }
  }
  const int col = n0 + wv * 16 + l15;
  const float bias = b_ih[col] + (col < 512 ? b_hh[col] : 0.0f);
#pragma unroll
  for (int mt = 0; mt < 4; ++mt) {
#pragma unroll
    for (int r = 0; r < 4; ++r) {
      const int m = m0 + mt * 16 + quad * 4 + r;
      gx[((size_t)(m >> 5) * kG + col) * 32 + (m & 31)] = (_Float16)(acc[mt][r] + bias);
    }
  }
}

union Frag8 {
  bf16x8 v;
  uint2 u2[2];
};

// One WG per (dir, batch-half): 16 batch rows, 512 threads (8 waves).
// v6 = v3 dataflow + DOUBLE-BUFFERED hlds -> ONE __syncthreads per step.
//   Step i reads hlds[i&1], writes hlds[(i&1)^1], barriers once. Step i+1's
//   writes to hlds[i&1] are safe: every wave passed the end-of-step-i barrier,
//   which is after all step-i reads of hlds[i&1]. This deletes one all-wave
//   sync + drain per step and un-splits the gate tail. Standard __syncthreads
//   only (raw s_barrier pattern retired after 2x container failures).
// LAYER 0: out = bf16 [S][2][32][256] written via hlds b128 read + dwordx4 store.
// LAYER 1: out = fp32 [B][S][512] scalar stores (full precision).
template <int LAYER>
__global__ __launch_bounds__(512, 2) void gru_scan(
    const _Float16* __restrict__ gx,  // [S][768][32] (incl. b_ih + b_hh for r,z)
    const float* __restrict__ W_hh,   // [768][256]
    const float* __restrict__ b_hh,   // [768] (only n-part used here)
    void* __restrict__ outv,
    float* __restrict__ hn) {         // [2][32][256] slab for this layer
  __shared__ short hlds[2][16][264];  // ping-pong; stride 264 = 16B-aligned rows
  __shared__ short wlds[768][36];     // kb=7 slice; stride 36 shorts = 72B

  const int tid = threadIdx.x;
  const int lane = tid & 63;
  const int w = tid >> 6;
  const int quad = lane >> 4, l15 = lane & 15;
  const int dir = blockIdx.x & 1;
  const int bbase = (blockIdx.x >> 1) * 16;

  for (int i = tid; i < 2 * 16 * 264; i += 512) (&hlds[0][0][0])[i] = 0;

  {  // stage W_hh[:, 224:256] -> LDS (bf16)
    const int kq = tid & 3, rb = tid >> 2;
#pragma unroll
    for (int j = 0; j < 6; ++j) {
      const int row = rb + j * 128;
      float v[8];
      load8(W_hh + (size_t)row * kH + 224 + kq * 8, v);
#pragma unroll
      for (int e = 0; e < 8; ++e) wlds[row][kq * 8 + e] = f2bf(v[e]);
    }
  }

  const int colH0 = w * 32 + l15;
  bf16x8 Bf[3][2][7];  // kb 0..6 register-resident
#pragma unroll
  for (int g3 = 0; g3 < 3; ++g3)
#pragma unroll
    for (int nt = 0; nt < 2; ++nt)
#pragma unroll
      for (int kb = 0; kb < 7; ++kb) {
        const int row = g3 * 256 + colH0 + nt * 16;
        float v[8];
        load8(W_hh + (size_t)row * kH + kb * 32 + quad * 8, v);
        bf16x8 f;
#pragma unroll
        for (int e = 0; e < 8; ++e) f[e] = f2bf(v[e]);
        Bf[g3][nt][kb] = f;
      }

  const float bhn[2] = {b_hh[512 + colH0], b_hh[512 + colH0 + 16]};
  float hprev[8] = {0, 0, 0, 0, 0, 0, 0, 0};

  short* out0 = (short*)outv;
  float* out1 = (float*)outv;

  __syncthreads();

  for (int i = 0; i < kS; ++i) {
    const int t = dir ? (kS - 1 - i) : i;
    const _Float16* gxt = gx + (size_t)t * (kG * 32);
    const short(*hbuf)[264] = hlds[i & 1];   // h(t-1)
    short(*hnext)[264] = hlds[(i & 1) ^ 1];  // h(t)

    // gx loads issued first; latency hidden under the r/n MFMA chains.
    f16x4 gxv[3][2];
#pragma unroll
    for (int g3 = 0; g3 < 3; ++g3)
#pragma unroll
      for (int nt = 0; nt < 2; ++nt)
        gxv[g3][nt] = *(const f16x4*)(gxt + (size_t)(g3 * 256 + colH0 + nt * 16) * 32 +
                                      bbase + quad * 4);

    // A-frags (h(t-1)) loaded ONCE, shared by all three gate chains.
    bf16x8 af[8];
#pragma unroll
    for (int kb = 0; kb < 8; ++kb)
      af[kb] = *(const bf16x8*)&hbuf[l15][kb * 32 + quad * 8];

    f32x4 C0[2] = {}, C1[2] = {}, C2[2] = {};

#define CHAIN(G3, CC)                                                              \
  {                                                                                \
    _Pragma("unroll") for (int kb = 0; kb < 7; ++kb) {                             \
      _Pragma("unroll") for (int nt = 0; nt < 2; ++nt) CC[nt] =                    \
          __builtin_amdgcn_mfma_f32_16x16x32_bf16(af[kb], Bf[G3][nt][kb], CC[nt], 0, 0, 0); \
    }                                                                              \
    _Pragma("unroll") for (int nt = 0; nt < 2; ++nt) {                             \
      Frag8 bf;                                                                    \
      const int row = G3 * 256 + colH0 + nt * 16;                                  \
      bf.u2[0] = *(const uint2*)&wlds[row][quad * 8];                              \
      bf.u2[1] = *(const uint2*)&wlds[row][quad * 8 + 4];                          \
      CC[nt] = __builtin_amdgcn_mfma_f32_16x16x32_bf16(af[7], bf.v, CC[nt], 0, 0, 0); \
    }                                                                              \
  }

    CHAIN(0, C0)  // r-gate accumulators first
    CHAIN(2, C2)  // n-gate

    float rr[2][4];  // r sigmoids overlap the z-chain below
#pragma unroll
    for (int nt = 0; nt < 2; ++nt)
#pragma unroll
      for (int r = 0; r < 4; ++r)
        rr[nt][r] = fast_sigmoid((float)gxv[0][nt][r] + C0[nt][r]);

    CHAIN(1, C1)  // z-gate last

    float nn[2][4];
#pragma unroll
    for (int nt = 0; nt < 2; ++nt)
#pragma unroll
      for (int r = 0; r < 4; ++r)
        nn[nt][r] = fast_tanh((float)gxv[2][nt][r] + rr[nt][r] * (C2[nt][r] + bhn[nt]));

    // Gate tail + h update + writes to the OTHER buffer: barrier-free region.
#pragma unroll
    for (int nt = 0; nt < 2; ++nt) {
#pragma unroll
      for (int r = 0; r < 4; ++r) {
        const float zz = fast_sigmoid((float)gxv[1][nt][r] + C1[nt][r]);
        const int e = nt * 4 + r;
        const float h = nn[nt][r] + zz * (hprev[e] - nn[nt][r]);
        hprev[e] = h;
        hnext[quad * 4 + r][colH0 + nt * 16] = f2bf(h);
        if constexpr (LAYER == 1) {
          out1[((size_t)(bbase + quad * 4 + r) * kS + t) * 512 + dir * 256 + colH0 +
               nt * 16] = h;
        }
      }
    }

    __syncthreads();  // single barrier: h(t) visible; all reads of hbuf done

    if constexpr (LAYER == 0) {  // vectorized bf16 out0 store via hnext
      const int srow = tid >> 5, schunk = tid & 31;
      *(uint4*)(out0 + (((size_t)t * 2 + dir) * 32 + bbase + srow) * 256 + schunk * 8) =
          *(const uint4*)&hnext[srow][schunk * 8];
    }
  }
#undef CHAIN

#pragma unroll
  for (int nt = 0; nt < 2; ++nt)
#pragma unroll
    for (int r = 0; r < 4; ++r)
      hn[(size_t)(dir * kB + bbase + quad * 4 + r) * kH + colH0 + nt * 16] =
          hprev[nt * 4 + r];
}

extern "C" void kernel_launch(void* const* d_in, const int* in_sizes, int n_in,
                              void* d_out, int out_size, void* d_ws, size_t ws_size,
                              hipStream_t stream) {
  const float* x     = (const float*)d_in[0];  // [B][S][256]
  const float* W_ih0 = (const float*)d_in[1];  // [768][256]
  const float* W_hh0 = (const float*)d_in[2];  // [768][256]
  const float* b_ih0 = (const float*)d_in[3];
  const float* b_hh0 = (const float*)d_in[4];
  const float* W_ih1 = (const float*)d_in[5];  // [768][512]
  const float* W_hh1 = (const float*)d_in[6];  // [768][256]
  const float* b_ih1 = (const float*)d_in[7];
  const float* b_hh1 = (const float*)d_in[8];

  float* out1 = (float*)d_out;                  // [B][S][512]
  float* hn = out1 + (size_t)kB * kS * 512;     // [4][B][H]

  _Float16* gxb = (_Float16*)d_ws;  // [S][768][32] fp16 (96 MB)
  short* out0 = (short*)((char*)d_ws + (size_t)kS * kB * kG * 2);  // bf16 [S][2][32][256] (64 MB)

  dim3 ggrid(kG / 64, (kS * kB) / 64);

  // Layer 0
  gemm_gx<0><<<ggrid, 256, 0, stream>>>(x, W_ih0, b_ih0, b_hh0, gxb);
  gru_scan<0><<<dim3(4), 512, 0, stream>>>(gxb, W_hh0, b_hh0, out0, hn);
  // Layer 1
  gemm_gx<1><<<ggrid, 256, 0, stream>>>(out0, W_ih1, b_ih1, b_hh1, gxb);
  gru_scan<1><<<dim3(4), 512, 0, stream>>>(gxb, W_hh1, b_hh1, out1, hn + 2 * kB * kH);
}

// Round 7
// 6704.145 us; speedup vs baseline: 1.3140x; 1.1325x over previous
//
#include <hip/hip_runtime.h>

typedef __attribute__((ext_vector_type(4))) float f32x4;
typedef __attribute__((ext_vector_type(8))) short bf16x8;
typedef __attribute__((ext_vector_type(4))) _Float16 f16x4;

constexpr int kB = 32;    // batch
constexpr int kS = 2048;  // seq len
constexpr int kH = 256;   // hidden
constexpr int kG = 768;   // 3*H

__device__ __forceinline__ short f2bf(float f) {
  unsigned u = __builtin_bit_cast(unsigned, f);
  u += 0x7fffu + ((u >> 16) & 1u);  // RNE
  return (short)(u >> 16);
}

__device__ __forceinline__ float fast_sigmoid(float x) {
  // 1/(1+2^(-x*log2e)) : mul, exp2, add, rcp (4 ops)
  return __builtin_amdgcn_rcpf(1.0f + __builtin_amdgcn_exp2f(x * -1.4426950408889634f));
}
__device__ __forceinline__ float fast_tanh(float x) {
  float e = __builtin_amdgcn_exp2f(x * 2.8853900817779268f);  // e^(2x)
  return 1.0f - 2.0f * __builtin_amdgcn_rcpf(1.0f + e);
}

__device__ __forceinline__ void load8(const float* p, float v[8]) {
  const float4 a = *(const float4*)p;
  const float4 b = *(const float4*)(p + 4);
  v[0] = a.x; v[1] = a.y; v[2] = a.z; v[3] = a.w;
  v[4] = b.x; v[5] = b.y; v[6] = b.z; v[7] = b.w;
}

// gx[t][g][b] = sum_k A[b][t][k] * W[g][k] + b_ih[g] + (g<512 ? b_hh[g] : 0)
// LAYER 0: A = fp32 [B][S][256].  LAYER 1: A = bf16 out0 [S][2][32][256] (K=512).
template <int LAYER>
__global__ __launch_bounds__(256) void gemm_gx(
    const void* __restrict__ Av, const float* __restrict__ W,
    const float* __restrict__ b_ih, const float* __restrict__ b_hh,
    _Float16* __restrict__ gx) {
  constexpr int K = (LAYER == 0) ? 256 : 512;
  __shared__ short As[64][40];  // stride 40 shorts = 80B: 16B-aligned rows, 2-way banks (free)
  __shared__ short Ws[64][40];
  const int tid = threadIdx.x;
  const int lane = tid & 63, wv = tid >> 6;
  const int quad = lane >> 4, l15 = lane & 15;
  const int m0 = blockIdx.y * 64, n0 = blockIdx.x * 64;
  const int srow = tid >> 2, kq = tid & 3;
  const int am = m0 + srow;
  const int b = am & 31, s = am >> 5;
  const float* Wrow = W + (size_t)(n0 + srow) * K;
  const float* Af = (const float*)Av + ((size_t)b * kS + s) * 256;
  const short* Ab = (const short*)Av + ((size_t)s * 64 + b) * 256;  // [s][dir][32][256]

  f32x4 acc[4] = {};

  for (int k0 = 0; k0 < K; k0 += 32) {
    const int k = k0 + kq * 8;
    short avs[8];
    if constexpr (LAYER == 0) {
      float v[8];
      load8(Af + k, v);
#pragma unroll
      for (int j = 0; j < 8; ++j) avs[j] = f2bf(v[j]);
    } else {
      *(uint4*)avs = *(const uint4*)(Ab + (size_t)(k >> 8) * 8192 + (k & 255));
    }
    float wv8[8];
    load8(Wrow + k, wv8);
    __syncthreads();  // previous iteration's LDS reads complete
#pragma unroll
    for (int j = 0; j < 8; ++j) As[srow][kq * 8 + j] = avs[j];
#pragma unroll
    for (int j = 0; j < 8; ++j) Ws[srow][kq * 8 + j] = f2bf(wv8[j]);
    __syncthreads();
    const bf16x8 bf = *(const bf16x8*)&Ws[wv * 16 + l15][quad * 8];
#pragma unroll
    for (int mt = 0; mt < 4; ++mt) {
      const bf16x8 af = *(const bf16x8*)&As[mt * 16 + l15][quad * 8];
      acc[mt] = __builtin_amdgcn_mfma_f32_16x16x32_bf16(af, bf, acc[mt], 0, 0, 0);
    }
  }
  const int col = n0 + wv * 16 + l15;
  const float bias = b_ih[col] + (col < 512 ? b_hh[col] : 0.0f);
#pragma unroll
  for (int mt = 0; mt < 4; ++mt) {
#pragma unroll
    for (int r = 0; r < 4; ++r) {
      const int m = m0 + mt * 16 + quad * 4 + r;
      gx[((size_t)(m >> 5) * kG + col) * 32 + (m & 31)] = (_Float16)(acc[mt][r] + bias);
    }
  }
}

union Frag8 {
  bf16x8 v;
  uint2 u2[2];
};

// v7: 1024-thread WG (16 waves, 4 waves/SIMD) — each wave owns 16 cols.
//   v6 counters showed VALUBusy+MfmaUtil ~ 89% with minimal overlap at
//   2 waves/SIMD: the step serializes [MFMA-latency window][VALU tail].
//   Doubling waves/SIMD halves per-wave work (24 MFMA, 12 trans) and lets
//   wave-stagger overlap one wave's MFMA chain with another's transcendentals.
//   Register budget (<=128/wave forced by 1024-thread WG): Bf kb0..5 in regs
//   (72), kb6/7 via two wlds slabs; af read in two 4-frag batches with a
//   sched_barrier between (live <=16); kb-outer joint gate loop (3-way ILP).
//   Keeps v6's dbuf hlds + single __syncthreads per step.
// LAYER 0: out = bf16 [S][2][32][256] via hlds uint2 stores.
// LAYER 1: out = fp32 [B][S][512] scalar stores.
template <int LAYER>
__global__ __launch_bounds__(1024) void gru_scan(
    const _Float16* __restrict__ gx,  // [S][768][32] (incl. b_ih + b_hh for r,z)
    const float* __restrict__ W_hh,   // [768][256]
    const float* __restrict__ b_hh,   // [768] (only n-part used here)
    void* __restrict__ outv,
    float* __restrict__ hn) {         // [2][32][256] slab for this layer
  __shared__ short hlds[2][16][264];    // ping-pong; stride 264 = 16B-aligned rows
  __shared__ short wlds[2][768][36];    // kb=6 / kb=7 slabs; stride 36 shorts

  const int tid = threadIdx.x;
  const int lane = tid & 63;
  const int w = tid >> 6;  // 0..15
  const int quad = lane >> 4, l15 = lane & 15;
  const int dir = blockIdx.x & 1;
  const int bbase = (blockIdx.x >> 1) * 16;

  for (int i = tid; i < 2 * 16 * 264; i += 1024) (&hlds[0][0][0])[i] = 0;

  {  // stage W_hh[:, 192:224] and [:, 224:256] -> wlds slabs (bf16)
    const int kq = tid & 3, rb = tid >> 2;  // rb 0..255
#pragma unroll
    for (int j = 0; j < 3; ++j) {
      const int row = rb + j * 256;
#pragma unroll
      for (int s = 0; s < 2; ++s) {
        float v[8];
        load8(W_hh + (size_t)row * kH + 192 + s * 32 + kq * 8, v);
#pragma unroll
        for (int e = 0; e < 8; ++e) wlds[s][row][kq * 8 + e] = f2bf(v[e]);
      }
    }
  }

  const int col = w * 16 + l15;  // this thread's single output column (0..255)
  bf16x8 Bf[3][6];               // kb 0..5 register-resident (72 VGPR/AGPR)
#pragma unroll
  for (int g3 = 0; g3 < 3; ++g3)
#pragma unroll
    for (int kb = 0; kb < 6; ++kb) {
      const int row = g3 * 256 + col;
      float v[8];
      load8(W_hh + (size_t)row * kH + kb * 32 + quad * 8, v);
      bf16x8 f;
#pragma unroll
      for (int e = 0; e < 8; ++e) f[e] = f2bf(v[e]);
      Bf[g3][kb] = f;
    }

  const float bhn = b_hh[512 + col];
  float hprev[4] = {0, 0, 0, 0};

  short* out0 = (short*)outv;
  float* out1 = (float*)outv;

  __syncthreads();

  for (int i = 0; i < kS; ++i) {
    const int t = dir ? (kS - 1 - i) : i;
    const _Float16* gxt = gx + (size_t)t * (kG * 32);
    const short(*hbuf)[264] = hlds[i & 1];   // h(t-1)
    short(*hnext)[264] = hlds[(i & 1) ^ 1];  // h(t)

    // gx loads issued first; latency hidden under the MFMA phase.
    f16x4 gxv[3];
#pragma unroll
    for (int g3 = 0; g3 < 3; ++g3)
      gxv[g3] = *(const f16x4*)(gxt + (size_t)(g3 * 256 + col) * 32 + bbase + quad * 4);

    f32x4 C[3] = {};  // r, z, n accumulators (3-way MFMA ILP, kb-outer)

    // ---- half 1: kb 0..3 (register B-frags); af live <= 4 frags ----
    {
      bf16x8 af[4];
#pragma unroll
      for (int kb = 0; kb < 4; ++kb)
        af[kb] = *(const bf16x8*)&hbuf[l15][kb * 32 + quad * 8];
#pragma unroll
      for (int kb = 0; kb < 4; ++kb)
#pragma unroll
        for (int g3 = 0; g3 < 3; ++g3)
          C[g3] = __builtin_amdgcn_mfma_f32_16x16x32_bf16(af[kb], Bf[g3][kb], C[g3], 0, 0, 0);
    }
    __builtin_amdgcn_sched_barrier(0);  // keep half-2 af reads from hoisting (reg cap)
    // ---- half 2: kb 4,5 (register B) + kb 6,7 (wlds B) ----
    {
      bf16x8 af[4];
#pragma unroll
      for (int k2 = 0; k2 < 4; ++k2)
        af[k2] = *(const bf16x8*)&hbuf[l15][(4 + k2) * 32 + quad * 8];
#pragma unroll
      for (int k2 = 0; k2 < 2; ++k2)
#pragma unroll
        for (int g3 = 0; g3 < 3; ++g3)
          C[g3] = __builtin_amdgcn_mfma_f32_16x16x32_bf16(af[k2], Bf[g3][4 + k2], C[g3], 0, 0, 0);
#pragma unroll
      for (int s = 0; s < 2; ++s)
#pragma unroll
        for (int g3 = 0; g3 < 3; ++g3) {
          Frag8 bf;
          bf.u2[0] = *(const uint2*)&wlds[s][g3 * 256 + col][quad * 8];
          bf.u2[1] = *(const uint2*)&wlds[s][g3 * 256 + col][quad * 8 + 4];
          C[g3] = __builtin_amdgcn_mfma_f32_16x16x32_bf16(af[2 + s], bf.v, C[g3], 0, 0, 0);
        }
    }

    // Gate tail: 4 h-elements per thread (12 transcendentals).
    float rr[4], nn[4];
#pragma unroll
    for (int r = 0; r < 4; ++r) rr[r] = fast_sigmoid((float)gxv[0][r] + C[0][r]);
#pragma unroll
    for (int r = 0; r < 4; ++r)
      nn[r] = fast_tanh((float)gxv[2][r] + rr[r] * (C[2][r] + bhn));
#pragma unroll
    for (int r = 0; r < 4; ++r) {
      const float zz = fast_sigmoid((float)gxv[1][r] + C[1][r]);
      const float h = nn[r] + zz * (hprev[r] - nn[r]);
      hprev[r] = h;
      hnext[quad * 4 + r][col] = f2bf(h);
      if constexpr (LAYER == 1) {
        out1[((size_t)(bbase + quad * 4 + r) * kS + t) * 512 + dir * 256 + col] = h;
      }
    }

    __syncthreads();  // single barrier: h(t) visible; all reads of hbuf done

    if constexpr (LAYER == 0) {  // bf16 out0 store via hnext (uint2 per thread)
      const int srow = tid >> 6, schunk = tid & 63;
      *(uint2*)(out0 + (((size_t)t * 2 + dir) * 32 + bbase + srow) * 256 + schunk * 4) =
          *(const uint2*)&hnext[srow][schunk * 4];
    }
  }

#pragma unroll
  for (int r = 0; r < 4; ++r)
    hn[(size_t)(dir * kB + bbase + quad * 4 + r) * kH + col] = hprev[r];
}

extern "C" void kernel_launch(void* const* d_in, const int* in_sizes, int n_in,
                              void* d_out, int out_size, void* d_ws, size_t ws_size,
                              hipStream_t stream) {
  const float* x     = (const float*)d_in[0];  // [B][S][256]
  const float* W_ih0 = (const float*)d_in[1];  // [768][256]
  const float* W_hh0 = (const float*)d_in[2];  // [768][256]
  const float* b_ih0 = (const float*)d_in[3];
  const float* b_hh0 = (const float*)d_in[4];
  const float* W_ih1 = (const float*)d_in[5];  // [768][512]
  const float* W_hh1 = (const float*)d_in[6];  // [768][256]
  const float* b_ih1 = (const float*)d_in[7];
  const float* b_hh1 = (const float*)d_in[8];

  float* out1 = (float*)d_out;                  // [B][S][512]
  float* hn = out1 + (size_t)kB * kS * 512;     // [4][B][H]

  _Float16* gxb = (_Float16*)d_ws;  // [S][768][32] fp16 (96 MB)
  short* out0 = (short*)((char*)d_ws + (size_t)kS * kB * kG * 2);  // bf16 [S][2][32][256] (64 MB)

  dim3 ggrid(kG / 64, (kS * kB) / 64);

  // Layer 0
  gemm_gx<0><<<ggrid, 256, 0, stream>>>(x, W_ih0, b_ih0, b_hh0, gxb);
  gru_scan<0><<<dim3(4), 1024, 0, stream>>>(gxb, W_hh0, b_hh0, out0, hn);
  // Layer 1
  gemm_gx<1><<<ggrid, 256, 0, stream>>>(out0, W_ih1, b_ih1, b_hh1, gxb);
  gru_scan<1><<<dim3(4), 1024, 0, stream>>>(gxb, W_hh1, b_hh1, out1, hn + 2 * kB * kH);
}